// Round 16
// baseline (308.496 us; speedup 1.0000x reference)
//
#include <hip/hip_runtime.h>
#include <hip/hip_bf16.h>
#include <math.h>
#include <type_traits>

#define B_    8
#define Nn    4096
#define Cc    320
#define QS    1024          // qkv row stride (padded from 960)
#define ATT_SCALE 0.15811388300841897f

typedef __attribute__((ext_vector_type(8))) short s8v;
typedef __attribute__((ext_vector_type(4))) float f4v;

__device__ __forceinline__ float bf2f(short u) {
    return __uint_as_float(((unsigned int)(unsigned short)u) << 16);
}
__device__ __forceinline__ short f2bf(float f) {
    return (short)__bfloat16_as_ushort(__float2bfloat16(f));
}
__device__ __forceinline__ float gelu_fast(float v) {
    float u = v * (0.7978845608f + 0.0356774081f * v * v);
    float e = __expf(2.f * u);
    float t = 1.f - 2.f / (e + 1.f);
    return 0.5f * v * (1.f + t);
}

typedef const __attribute__((address_space(1))) unsigned int* gp1_t;
typedef __attribute__((address_space(3))) unsigned int* lp3_t;
__device__ __forceinline__ void gload16(const void* g, void* l) {
    __builtin_amdgcn_global_load_lds((gp1_t)g, (lp3_t)l, 16, 0, 0);
}

// ---------------- all weights -> bf16 (padded), one launch ----------------
__global__ void cvt_all(const float* __restrict__ s0, const float* __restrict__ s1,
                        const float* __restrict__ s2, const float* __restrict__ s3,
                        __hip_bfloat16* __restrict__ d) {
    int i = blockIdx.x * 256 + threadIdx.x;
    if (i >= 1351680) return;
    const float* s; int j, rows, K;
    if (i < 327680)      { s = s0; j = i;          rows = 960;  K = 320; }
    else if (i < 450560) { s = s1; j = i - 327680; rows = 320;  K = 320; }
    else if (i < 860160) { s = s2; j = i - 450560; rows = 1280; K = 320; }
    else                 { s = s3; j = i - 860160; rows = 320;  K = 1280; }
    float v = (j / K < rows) ? s[j] : 0.f;
    d[i] = __float2bfloat16(v);
}

// ---------------- LayerNorm over C=320, one wave per token, bf16 out ----------------
template<typename T>
__global__ void ln_kernel(const T* __restrict__ x, const float* __restrict__ g,
                          const float* __restrict__ bt, __hip_bfloat16* __restrict__ out) {
    int bn = blockIdx.x;
    int lane = threadIdx.x;
    const T* row = x + (size_t)bn * Cc;
    float v[5];
    float s = 0.f, s2 = 0.f;
    #pragma unroll
    for (int i = 0; i < 5; ++i) {
        if constexpr (std::is_same<T, float>::value) v[i] = row[lane + 64 * i];
        else v[i] = bf2f(((const short*)row)[lane + 64 * i]);
        s += v[i];
        s2 += v[i] * v[i];
    }
    #pragma unroll
    for (int off = 32; off > 0; off >>= 1) {
        s  += __shfl_down(s, off);
        s2 += __shfl_down(s2, off);
    }
    s  = __shfl(s, 0);
    s2 = __shfl(s2, 0);
    float mean = s * (1.f / 320.f);
    float var  = s2 * (1.f / 320.f) - mean * mean;
    float rstd = rsqrtf(var + 1e-6f);
    __hip_bfloat16* orow = out + (size_t)bn * Cc;
    #pragma unroll
    for (int i = 0; i < 5; ++i) {
        int c = lane + 64 * i;
        orow[c] = __float2bfloat16((v[i] - mean) * rstd * g[c] + bt[c]);
    }
}

// ---------------- bf16 MFMA GEMM, 256x128 tile, BK=64 (R12 proven, 0 conflicts) ----
// 1-D grid with XCD-grouping: blocks sharing an A-panel get ids spaced 8 apart.
template<int ACT, int RES, int WF32, int WBF16, int KT>
__global__ __launch_bounds__(512) void gemm_mfma(
        const __hip_bfloat16* __restrict__ A, const __hip_bfloat16* __restrict__ W,
        const float* __restrict__ bias, const void* __restrict__ resv,
        float* __restrict__ outf, __hip_bfloat16* __restrict__ outb,
        int NS, int Nreal, int gy) {
    __shared__ __align__(16) short As[256 * 64];
    __shared__ __align__(16) short Bs[128 * 64];
    int bid = blockIdx.x;
    int grp8 = gy << 3;
    int grp = bid / grp8, rem = bid % grp8;
    int m0 = ((grp << 3) + (rem & 7)) << 8;
    int n0 = (rem >> 3) << 7;
    int tid = threadIdx.x;
    int w = tid >> 6, lane = tid & 63;
    int wr = w >> 1, wc = w & 1;
    int lrow = lane & 15, lk = lane >> 4;
    f4v acc[4][4];
    #pragma unroll
    for (int i = 0; i < 4; ++i)
        #pragma unroll
        for (int j = 0; j < 4; ++j) acc[i][j] = (f4v){0.f, 0.f, 0.f, 0.f};

    int srow = (w << 3) + (lane >> 3);
    int slot = lane & 7;

    #pragma unroll
    for (int k0 = 0; k0 < KT; k0 += 64) {
        __syncthreads();
        #pragma unroll
        for (int i = 0; i < 4; ++i) {
            int row = i * 64 + srow;
            int sk = (slot ^ (row & 7)) << 3;
            gload16(&A[(size_t)(m0 + row) * KT + k0 + sk], &As[i * 4096 + w * 512]);
        }
        #pragma unroll
        for (int i = 0; i < 2; ++i) {
            int row = i * 64 + srow;
            int sk = (slot ^ (row & 7)) << 3;
            gload16(&W[(size_t)(n0 + row) * KT + k0 + sk], &Bs[i * 4096 + w * 512]);
        }
        __syncthreads();
        #pragma unroll
        for (int ks = 0; ks < 2; ++ks) {
            s8v af[4], bf[4];
            #pragma unroll
            for (int mi = 0; mi < 4; ++mi) {
                int row = wr * 64 + mi * 16 + lrow;
                int s = (ks * 4 + lk) ^ (row & 7);
                af[mi] = *reinterpret_cast<const s8v*>(&As[row * 64 + s * 8]);
            }
            #pragma unroll
            for (int ni = 0; ni < 4; ++ni) {
                int row = wc * 64 + ni * 16 + lrow;
                int s = (ks * 4 + lk) ^ (row & 7);
                bf[ni] = *reinterpret_cast<const s8v*>(&Bs[row * 64 + s * 8]);
            }
            #pragma unroll
            for (int mi = 0; mi < 4; ++mi)
                #pragma unroll
                for (int ni = 0; ni < 4; ++ni)
                    acc[mi][ni] = __builtin_amdgcn_mfma_f32_16x16x32_bf16(bf[ni], af[mi], acc[mi][ni], 0, 0, 0);
        }
    }
    #pragma unroll
    for (int mi = 0; mi < 4; ++mi) {
        int m = m0 + wr * 64 + mi * 16 + lrow;
        #pragma unroll
        for (int ni = 0; ni < 4; ++ni) {
            int n = n0 + wc * 64 + ni * 16 + (lk << 2);
            if (n >= Nreal) continue;
            f4v v4 = acc[mi][ni];
            float4 bv = *reinterpret_cast<const float4*>(&bias[n]);
            v4[0] += bv.x; v4[1] += bv.y; v4[2] += bv.z; v4[3] += bv.w;
            if (RES == 1) {
                const float* res = (const float*)resv;
                float4 rv = *reinterpret_cast<const float4*>(&res[(size_t)m * NS + n]);
                v4[0] += rv.x; v4[1] += rv.y; v4[2] += rv.z; v4[3] += rv.w;
            } else if (RES == 2) {
                const short* res = (const short*)resv;
                short4 rv = *reinterpret_cast<const short4*>(&res[(size_t)m * NS + n]);
                v4[0] += bf2f(rv.x); v4[1] += bf2f(rv.y);
                v4[2] += bf2f(rv.z); v4[3] += bf2f(rv.w);
            }
            if (ACT == 1) {
                #pragma unroll
                for (int r = 0; r < 4; ++r) v4[r] = gelu_fast(v4[r]);
            }
            if (WF32)
                *reinterpret_cast<float4*>(&outf[(size_t)m * NS + n]) =
                    make_float4(v4[0], v4[1], v4[2], v4[3]);
            if (WBF16) {
                ushort4 u;
                u.x = (unsigned short)f2bf(v4[0]);
                u.y = (unsigned short)f2bf(v4[1]);
                u.z = (unsigned short)f2bf(v4[2]);
                u.w = (unsigned short)f2bf(v4[3]);
                *reinterpret_cast<ushort4*>(&outb[(size_t)m * NS + n]) = u;
            }
        }
    }
}

// ------ full-N GEMM (N=320), BK=32 DOUBLE-BUFFERED counted-vmcnt pipeline ------
// tile M=64 x N=320, 512 threads, 8 waves 2m x 4n. A read ONCE per block.
// Per step 1536 staging units of 16B = exactly 3 gload16/thread (wave-uniform):
// issue 0: waves 0-3 -> A, waves 4-7 -> W; issues 1-2: all W. vmcnt(3) exact.
template<int ACT, int RES, int WF32, int WBF16, int KT, int LN>
__global__ __launch_bounds__(512) void gemm_fulln(
        const __hip_bfloat16* __restrict__ A, const __hip_bfloat16* __restrict__ W,
        const float* __restrict__ bias, const void* __restrict__ resv,
        float* __restrict__ outf, __hip_bfloat16* __restrict__ outb, int NS,
        const float* __restrict__ lng, const float* __restrict__ lnb,
        __hip_bfloat16* __restrict__ lnout) {
    constexpr int NSTEP = KT / 32;
    __shared__ __align__(16) short As[2][64 * 32];    //  8 KB
    __shared__ __align__(16) short Ws[2][320 * 32];   // 40 KB
    int tid = threadIdx.x;
    int m0 = blockIdx.x << 6;
    int w = tid >> 6, lane = tid & 63;
    int wr = w >> 2, wc = w & 3;
    int lrow = lane & 15, lk = lane >> 4;
    f4v acc[2][5];
    #pragma unroll
    for (int i = 0; i < 2; ++i)
        #pragma unroll
        for (int j = 0; j < 5; ++j) acc[i][j] = (f4v){0.f, 0.f, 0.f, 0.f};

    auto STAGE = [&](int buf, int k0) {
        #pragma unroll
        for (int i = 0; i < 3; ++i) {
            int u = tid + i * 512;
            if (i == 0 && w < 4) {               // wave-uniform branch
                int row = u >> 2, slot = u & 3;
                int sk = (slot ^ (row & 3)) << 3;
                gload16(&A[(size_t)(m0 + row) * KT + k0 + sk],
                        &As[buf][(w << 6) * 8]);
            } else {
                int uw = u - 256;
                int row = uw >> 2, slot = uw & 3;
                int sk = (slot ^ (row & 3)) << 3;
                gload16(&W[(size_t)row * KT + k0 + sk],
                        &Ws[buf][((w << 6) + i * 512 - 256) * 8]);
            }
        }
    };

    STAGE(0, 0);
    #pragma unroll
    for (int step = 0; step < NSTEP; ++step) {
        int buf = step & 1;
        if (step + 1 < NSTEP) {
            STAGE(buf ^ 1, (step + 1) * 32);
            asm volatile("s_waitcnt vmcnt(3)" ::: "memory");
        } else {
            asm volatile("s_waitcnt vmcnt(0)" ::: "memory");
        }
        __builtin_amdgcn_sched_barrier(0);
        __builtin_amdgcn_s_barrier();            // buf collectively ready
        s8v af[2], bf[5];
        #pragma unroll
        for (int mi = 0; mi < 2; ++mi) {
            int row = wr * 32 + mi * 16 + lrow;
            af[mi] = *reinterpret_cast<const s8v*>(&As[buf][row * 32 + ((lk ^ (row & 3)) << 3)]);
        }
        #pragma unroll
        for (int ni = 0; ni < 5; ++ni) {
            int row = wc * 80 + ni * 16 + lrow;
            bf[ni] = *reinterpret_cast<const s8v*>(&Ws[buf][row * 32 + ((lk ^ (row & 3)) << 3)]);
        }
        #pragma unroll
        for (int mi = 0; mi < 2; ++mi)
            #pragma unroll
            for (int ni = 0; ni < 5; ++ni)
                acc[mi][ni] = __builtin_amdgcn_mfma_f32_16x16x32_bf16(bf[ni], af[mi], acc[mi][ni], 0, 0, 0);
        __builtin_amdgcn_s_barrier();            // all reads of buf done
    }

    float psum[2] = {0.f, 0.f}, psq[2] = {0.f, 0.f};
    #pragma unroll
    for (int mi = 0; mi < 2; ++mi) {
        int rl = wr * 32 + mi * 16 + lrow;
        int m = m0 + rl;
        #pragma unroll
        for (int ni = 0; ni < 5; ++ni) {
            int n = wc * 80 + ni * 16 + (lk << 2);
            f4v v4 = acc[mi][ni];
            float4 bv = *reinterpret_cast<const float4*>(&bias[n]);
            v4[0] += bv.x; v4[1] += bv.y; v4[2] += bv.z; v4[3] += bv.w;
            if (RES == 1) {
                const float* res = (const float*)resv;
                float4 rv = *reinterpret_cast<const float4*>(&res[(size_t)m * NS + n]);
                v4[0] += rv.x; v4[1] += rv.y; v4[2] += rv.z; v4[3] += rv.w;
            } else if (RES == 2) {
                const short* res = (const short*)resv;
                short4 rv = *reinterpret_cast<const short4*>(&res[(size_t)m * NS + n]);
                v4[0] += bf2f(rv.x); v4[1] += bf2f(rv.y);
                v4[2] += bf2f(rv.z); v4[3] += bf2f(rv.w);
            }
            if (ACT == 1) {
                #pragma unroll
                for (int r = 0; r < 4; ++r) v4[r] = gelu_fast(v4[r]);
            }
            if (WF32)
                *reinterpret_cast<float4*>(&outf[(size_t)m * NS + n]) =
                    make_float4(v4[0], v4[1], v4[2], v4[3]);
            if (WBF16) {
                ushort4 u;
                u.x = (unsigned short)f2bf(v4[0]);
                u.y = (unsigned short)f2bf(v4[1]);
                u.z = (unsigned short)f2bf(v4[2]);
                u.w = (unsigned short)f2bf(v4[3]);
                *reinterpret_cast<ushort4*>(&outb[(size_t)m * NS + n]) = u;
            }
            if (LN) {
                acc[mi][ni] = v4;
                psum[mi] += v4[0] + v4[1] + v4[2] + v4[3];
                psq[mi]  += v4[0]*v4[0] + v4[1]*v4[1] + v4[2]*v4[2] + v4[3]*v4[3];
            }
        }
    }
    if (LN) {
        __syncthreads();
        float* red = (float*)As;                 // 2048 floats = 8 KB (= sizeof As)
        #pragma unroll
        for (int mi = 0; mi < 2; ++mi) {
            int rl = wr * 32 + mi * 16 + lrow;
            red[(rl * 16 + wc * 4 + lk) * 2]     = psum[mi];
            red[(rl * 16 + wc * 4 + lk) * 2 + 1] = psq[mi];
        }
        __syncthreads();
        float* st = (float*)Ws;
        if (tid < 64) {
            float s = 0.f, q = 0.f;
            #pragma unroll
            for (int p = 0; p < 16; ++p) {
                s += red[(tid * 16 + p) * 2];
                q += red[(tid * 16 + p) * 2 + 1];
            }
            float mean = s * (1.f / 320.f);
            float var  = q * (1.f / 320.f) - mean * mean;
            st[tid * 2]     = mean;
            st[tid * 2 + 1] = rsqrtf(var + 1e-6f);
        }
        __syncthreads();
        #pragma unroll
        for (int mi = 0; mi < 2; ++mi) {
            int rl = wr * 32 + mi * 16 + lrow;
            int m = m0 + rl;
            float mean = st[rl * 2], rstd = st[rl * 2 + 1];
            #pragma unroll
            for (int ni = 0; ni < 5; ++ni) {
                int n = wc * 80 + ni * 16 + (lk << 2);
                float4 g4 = *reinterpret_cast<const float4*>(&lng[n]);
                float4 b4 = *reinterpret_cast<const float4*>(&lnb[n]);
                f4v v4 = acc[mi][ni];
                ushort4 u;
                u.x = (unsigned short)f2bf((v4[0] - mean) * rstd * g4.x + b4.x);
                u.y = (unsigned short)f2bf((v4[1] - mean) * rstd * g4.y + b4.y);
                u.z = (unsigned short)f2bf((v4[2] - mean) * rstd * g4.z + b4.z);
                u.w = (unsigned short)f2bf((v4[3] - mean) * rstd * g4.w + b4.w);
                *reinterpret_cast<ushort4*>(&lnout[(size_t)m * Cc + n]) = u;
            }
        }
    }
}

// ---------------- CPE depthwise conv (k=3) + residual from LDS tile -> bf16 ----------
__global__ __launch_bounds__(256) void cpe_tile(
        const float* __restrict__ src, const float* __restrict__ wts,
        const float* __restrict__ bias, __hip_bfloat16* __restrict__ outb) {
    constexpr int P = 1, S = 18;
    __shared__ float vt[S * S * 8];
    __shared__ float ws_[8 * 9];
    int blk = blockIdx.x;
    int tile = blk & 15;
    int g  = (blk >> 4) % 40;
    int b  = (blk >> 4) / 40;
    int ty0 = (tile >> 2) << 4;
    int tx0 = (tile & 3) << 4;
    int c0 = g * 8;
    int tid = threadIdx.x;
    for (int e = tid; e < 72; e += 256) ws_[e] = wts[c0 * 9 + e];
    const float* sb = src + (size_t)b * Nn * Cc + c0;
    for (int e = tid; e < S * S; e += 256) {
        int hy = e / S, hx = e % S;
        int gy = ty0 - P + hy, gx = tx0 - P + hx;
        float px8[8];
        #pragma unroll
        for (int j = 0; j < 8; ++j) px8[j] = 0.f;
        if ((unsigned)gy < 64u && (unsigned)gx < 64u) {
            const float* p = &sb[(size_t)((gy << 6) + gx) * Cc];
            float4 lo = reinterpret_cast<const float4*>(p)[0];
            float4 hi = reinterpret_cast<const float4*>(p)[1];
            px8[0] = lo.x; px8[1] = lo.y; px8[2] = lo.z; px8[3] = lo.w;
            px8[4] = hi.x; px8[5] = hi.y; px8[6] = hi.z; px8[7] = hi.w;
        }
        #pragma unroll
        for (int j = 0; j < 8; ++j) vt[e * 8 + j] = px8[j];
    }
    __syncthreads();
    int cl  = tid & 7;
    int px  = (tid >> 3) & 15;
    int pyh = tid >> 7;
    int c = c0 + cl;
    float acc[8];
    float bval = bias[c];
    #pragma unroll
    for (int j = 0; j < 8; ++j) acc[j] = bval;
    #pragma unroll
    for (int dx = 0; dx < 3; ++dx) {
        float col[10];
        #pragma unroll
        for (int i = 0; i < 10; ++i)
            col[i] = vt[((pyh * 8 + i) * S + (px + dx)) * 8 + cl];
        #pragma unroll
        for (int j = 0; j < 8; ++j)
            #pragma unroll
            for (int dy = 0; dy < 3; ++dy)
                acc[j] += col[j + dy] * ws_[cl * 9 + dy * 3 + dx];
    }
    #pragma unroll
    for (int j = 0; j < 8; ++j) {
        int n = ((ty0 + pyh * 8 + j) << 6) + tx0 + px;
        size_t bn = (size_t)b * Nn + n;
        float ctr = vt[((pyh * 8 + j + P) * S + (px + P)) * 8 + cl];
        outb[bn * Cc + c] = __float2bfloat16(acc[j] + ctr);
    }
}

// ---------------- merged crpe conv (k3/k5/k7 in ONE launch) + att combine ------------
template<int KSZ>
__device__ __forceinline__ void crpe_body(
        float* vt, float* ws_, int tile, int b, int c0,
        const short* __restrict__ qkv, const float* __restrict__ wts,
        const float* __restrict__ bias,
        const short* __restrict__ fa0, const float* __restrict__ dg,
        short* __restrict__ outb) {
    constexpr int P = KSZ / 2;
    constexpr int S = 16 + 2 * P;
    int ty0 = (tile >> 2) << 4;
    int tx0 = (tile & 3) << 4;
    int tid = threadIdx.x;
    for (int e = tid; e < 8 * KSZ * KSZ; e += 256) ws_[e] = wts[e];
    const short* sb = qkv + (size_t)b * Nn * QS + 640 + c0;
    for (int e = tid; e < S * S; e += 256) {
        int hy = e / S, hx = e % S;
        int gy = ty0 - P + hy, gx = tx0 - P + hx;
        float px8[8];
        #pragma unroll
        for (int j = 0; j < 8; ++j) px8[j] = 0.f;
        if ((unsigned)gy < 64u && (unsigned)gx < 64u) {
            s8v v8 = *reinterpret_cast<const s8v*>(&sb[(size_t)((gy << 6) + gx) * QS]);
            #pragma unroll
            for (int j = 0; j < 8; ++j) px8[j] = bf2f(v8[j]);
        }
        #pragma unroll
        for (int j = 0; j < 8; ++j) vt[e * 8 + j] = px8[j];
    }
    __syncthreads();
    int cl  = tid & 7;
    int px  = (tid >> 3) & 15;
    int pyh = tid >> 7;
    int c = c0 + cl;
    float acc[8];
    float bval = bias[cl];
    #pragma unroll
    for (int j = 0; j < 8; ++j) acc[j] = bval;
    #pragma unroll
    for (int dx = 0; dx < KSZ; ++dx) {
        float col[8 + KSZ - 1];
        #pragma unroll
        for (int i = 0; i < 8 + KSZ - 1; ++i)
            col[i] = vt[((pyh * 8 + i) * S + (px + dx)) * 8 + cl];
        #pragma unroll
        for (int j = 0; j < 8; ++j)
            #pragma unroll
            for (int dy = 0; dy < KSZ; ++dy)
                acc[j] += col[j + dy] * ws_[cl * KSZ * KSZ + dy * KSZ + dx];
    }
    float dgv = dg[(size_t)b * Cc + c];
    #pragma unroll
    for (int j = 0; j < 8; ++j) {
        int n = ((ty0 + pyh * 8 + j) << 6) + tx0 + px;
        size_t bn = (size_t)b * Nn + n;
        float qv  = bf2f(qkv[bn * QS + c]);
        float fav = bf2f(fa0[bn * Cc + c]);
        float r = dgv * (ATT_SCALE * fav + qv * acc[j]);
        outb[bn * Cc + c] = __float2bfloat16(r);
    }
}

__global__ __launch_bounds__(256) void crpe_all(
        const __hip_bfloat16* __restrict__ qkv,
        const float* __restrict__ w3, const float* __restrict__ b3,
        const float* __restrict__ w5, const float* __restrict__ b5,
        const float* __restrict__ w7, const float* __restrict__ b7,
        const __hip_bfloat16* __restrict__ fa, const float* __restrict__ dg,
        __hip_bfloat16* __restrict__ outb) {
    __shared__ float vt[22 * 22 * 8];
    __shared__ float ws_[8 * 49];
    int blk = blockIdx.x;
    int tile = blk & 15;
    int g = (blk >> 4) % 40;
    int b = (blk >> 4) / 40;
    int c0 = g * 8;
    if (g < 10)
        crpe_body<3>(vt, ws_, tile, b, c0, (const short*)qkv,
                     w3 + c0 * 9, b3 + c0, (const short*)fa, dg, (short*)outb);
    else if (g < 25)
        crpe_body<5>(vt, ws_, tile, b, c0, (const short*)qkv,
                     w5 + (c0 - 80) * 25, b5 + (c0 - 80), (const short*)fa, dg, (short*)outb);
    else
        crpe_body<7>(vt, ws_, tile, b, c0, (const short*)qkv,
                     w7 + (c0 - 200) * 49, b7 + (c0 - 200), (const short*)fa, dg, (short*)outb);
}

// ---------------- kv + softmax-denominator via MFMA ----------------
__global__ __launch_bounds__(256) void kv_mfma(const __hip_bfloat16* __restrict__ qkv,
                                               float* __restrict__ kvp) {
    __shared__ short lds[4 * 2 * 48 * 66];
    int blk = blockIdx.x;
    int s = blk & 7;
    int bh = blk >> 3;
    int h = bh & 7, b = bh >> 3;
    int tid = threadIdx.x;
    int w = tid >> 6, lane = tid & 63;
    short* ke_t = lds + w * 2 * 48 * 66;
    short* vv_t = ke_t + 48 * 66;
    for (int e = lane; e < 8 * 66; e += 64) {
        ke_t[40 * 66 + e] = 0;
        vv_t[40 * 66 + e] = 0;
    }
    for (int n = lane; n < 66; n += 64) vv_t[40 * 66 + n] = (short)0x3F80;

    const short* kb = (const short*)qkv + (size_t)b * Nn * QS + 320 + h * 40;
    const short* vb = kb + 320;
    int col0 = lane & 15, kq = lane >> 4;
    f4v acc[3][3];
    #pragma unroll
    for (int i = 0; i < 3; ++i)
        #pragma unroll
        for (int j = 0; j < 3; ++j) acc[i][j] = (f4v){0.f, 0.f, 0.f, 0.f};

    for (int t = w; t < 8; t += 4) {
        int n0 = s * 512 + t * 64;
        for (int e = lane; e < 320; e += 64) {
            int nl = e / 5, oct = e % 5;
            size_t go = (size_t)(n0 + nl) * QS + oct * 8;
            s8v k8 = *reinterpret_cast<const s8v*>(kb + go);
            s8v v8 = *reinterpret_cast<const s8v*>(vb + go);
            #pragma unroll
            for (int j = 0; j < 8; ++j) {
                ke_t[(oct * 8 + j) * 66 + nl] = f2bf(__expf(bf2f(k8[j])));
                vv_t[(oct * 8 + j) * 66 + nl] = v8[j];
            }
        }
        __syncthreads();
        #pragma unroll
        for (int ks = 0; ks < 2; ++ks) {
            s8v af[3], bfr[3];
            #pragma unroll
            for (int mt = 0; mt < 3; ++mt)
                af[mt] = *reinterpret_cast<const s8v*>(ke_t + (mt * 16 + col0) * 66 + ks * 32 + kq * 8);
            #pragma unroll
            for (int nt = 0; nt < 3; ++nt)
                bfr[nt] = *reinterpret_cast<const s8v*>(vv_t + (nt * 16 + col0) * 66 + ks * 32 + kq * 8);
            #pragma unroll
            for (int mt = 0; mt < 3; ++mt)
                #pragma unroll
                for (int nt = 0; nt < 3; ++nt)
                    acc[mt][nt] = __builtin_amdgcn_mfma_f32_16x16x32_bf16(af[mt], bfr[nt], acc[mt][nt], 0, 0, 0);
        }
        __syncthreads();
    }
    float* red = (float*)lds;
    #pragma unroll
    for (int mt = 0; mt < 3; ++mt) {
        #pragma unroll
        for (int nt = 0; nt < 3; ++nt) {
            #pragma unroll
            for (int r = 0; r < 4; ++r) {
                int ch = mt * 16 + kq * 4 + r;
                int cv = nt * 16 + col0;
                if (ch < 40) red[w * 1920 + ch * 48 + cv] = acc[mt][nt][r];
            }
        }
    }
    __syncthreads();
    for (int p = tid; p < 1920; p += 256) {
        float sv = red[p] + red[1920 + p] + red[2 * 1920 + p] + red[3 * 1920 + p];
        kvp[(size_t)blk * 1920 + p] = sv;
    }
}

__global__ void kv_combine2(const float* __restrict__ kvp, float* __restrict__ kv) {
    int bh = blockIdx.x;
    int tid = threadIdx.x;
    __shared__ float sinv[40];
    if (tid < 40) {
        float S = 0.f;
        for (int s2 = 0; s2 < 8; ++s2)
            S += kvp[(size_t)(bh * 8 + s2) * 1920 + tid * 48 + 40];
        sinv[tid] = 1.f / S;
    }
    __syncthreads();
    for (int p = tid; p < 1600; p += 256) {
        int ch = p / 40, cv = p % 40;
        float v = 0.f;
        for (int s2 = 0; s2 < 8; ++s2)
            v += kvp[(size_t)(bh * 8 + s2) * 1920 + ch * 48 + cv];
        kv[(size_t)bh * 1600 + p] = v * sinv[ch];
    }
}

// ---------------- domain gate ----------------
__global__ void dgate_kernel(const float* __restrict__ lbl, const float* __restrict__ w1,
                             const float* __restrict__ b1, const float* __restrict__ w2,
                             const float* __restrict__ b2, float* __restrict__ dg) {
    int b = blockIdx.x;
    int tid = threadIdx.x;
    __shared__ float hid[160];
    __shared__ float dd[320];
    if (tid < 160) {
        float a = b1[tid];
        for (int d = 0; d < 4; ++d) a += w1[tid * 4 + d] * lbl[b * 4 + d];
        hid[tid] = fmaxf(a, 0.f);
    }
    __syncthreads();
    float a = b2[tid];
    for (int j = 0; j < 160; ++j) a += w2[tid * 160 + j] * hid[j];
    dd[tid] = a;
    __syncthreads();
    if (tid < 40) {
        float M = -1e30f;
        for (int h2 = 0; h2 < 8; ++h2) M = fmaxf(M, dd[h2 * 40 + tid]);
        float S = 0.f;
        float e[8];
        for (int h2 = 0; h2 < 8; ++h2) { e[h2] = __expf(dd[h2 * 40 + tid] - M); S += e[h2]; }
        float inv = 1.f / S;
        for (int h2 = 0; h2 < 8; ++h2) dg[b * 320 + h2 * 40 + tid] = e[h2] * inv;
    }
}

// ---------------- fa = q @ kv, one token per thread, bf16 out ----------------
__global__ __launch_bounds__(256) void fa_kernel(const __hip_bfloat16* __restrict__ qkv,
        const float* __restrict__ kvmat, __hip_bfloat16* __restrict__ fa) {
    __shared__ float kvs[1600];
    int blk = blockIdx.x;
    int chunk = blk & 15;
    int bh = blk >> 4;
    int h = bh & 7, b = bh >> 3;
    int tid = threadIdx.x;
    for (int e = tid; e < 1600; e += 256) kvs[e] = kvmat[(size_t)bh * 1600 + e];
    __syncthreads();
    int n = chunk * 256 + tid;
    const short* qr = (const short*)qkv + (size_t)(b * Nn + n) * QS + h * 40;
    float q[40];
    #pragma unroll
    for (int i = 0; i < 5; ++i) {
        s8v v8 = reinterpret_cast<const s8v*>(qr)[i];
        #pragma unroll
        for (int j = 0; j < 8; ++j) q[i * 8 + j] = bf2f(v8[j]);
    }
    float o[40];
    #pragma unroll
    for (int cv = 0; cv < 40; ++cv) o[cv] = 0.f;
    #pragma unroll
    for (int ch = 0; ch < 40; ++ch) {
        float qv = q[ch];
        #pragma unroll
        for (int cv = 0; cv < 40; ++cv)
            o[cv] += qv * kvs[ch * 40 + cv];
    }
    short* fr = (short*)fa + (size_t)(b * Nn + n) * 320 + h * 40;
    #pragma unroll
    for (int i = 0; i < 5; ++i) {
        s8v u;
        #pragma unroll
        for (int j = 0; j < 8; ++j) u[j] = f2bf(o[i * 8 + j]);
        *reinterpret_cast<s8v*>(fr + i * 8) = u;
    }
}

extern "C" void kernel_launch(void* const* d_in, const int* in_sizes, int n_in,
                              void* d_out, int out_size, void* d_ws, size_t ws_size,
                              hipStream_t stream) {
    const float* x     = (const float*)d_in[0];
    const float* lbl   = (const float*)d_in[1];
    const float* cpe_w = (const float*)d_in[2];
    const float* cpe_b = (const float*)d_in[3];
    const float* ln1g  = (const float*)d_in[4];
    const float* ln1b  = (const float*)d_in[5];
    const float* qkv_w = (const float*)d_in[6];
    const float* qkv_b = (const float*)d_in[7];
    const float* w3    = (const float*)d_in[8];
    const float* b3    = (const float*)d_in[9];
    const float* w5    = (const float*)d_in[10];
    const float* b5    = (const float*)d_in[11];
    const float* w7    = (const float*)d_in[12];
    const float* b7    = (const float*)d_in[13];
    const float* dw1   = (const float*)d_in[14];
    const float* db1   = (const float*)d_in[15];
    const float* dw2   = (const float*)d_in[16];
    const float* db2   = (const float*)d_in[17];
    const float* pw    = (const float*)d_in[18];
    const float* pb    = (const float*)d_in[19];
    const float* ln2g  = (const float*)d_in[20];
    const float* ln2b  = (const float*)d_in[21];
    const float* m1w   = (const float*)d_in[22];
    const float* m1b   = (const float*)d_in[23];
    const float* m2w   = (const float*)d_in[24];
    const float* m2b   = (const float*)d_in[25];
    float* out = (float*)d_out;

    float* ws = (float*)d_ws;
    __hip_bfloat16* x1b  = (__hip_bfloat16*)ws; ws += 5242880;
    __hip_bfloat16* qkvb = (__hip_bfloat16*)ws; ws += 16777216;
    float* big  = ws; ws += 20971520;
    __hip_bfloat16* gelub = (__hip_bfloat16*)big;
    __hip_bfloat16* fab   = (__hip_bfloat16*)ws; ws += 5242880;
    __hip_bfloat16* bb1   = (__hip_bfloat16*)ws; ws += 5242880;
    __hip_bfloat16* wb    = (__hip_bfloat16*)ws; ws += 675840;
    float* kvp  = ws; ws += 983040;
    float* kv   = ws; ws += 102400;
    float* dg   = ws; ws += 2560;
    __hip_bfloat16* wbq  = wb;
    __hip_bfloat16* wbp  = wbq  + 1024 * 320;
    __hip_bfloat16* wbm1 = wbp  + 384 * 320;
    __hip_bfloat16* wbm2 = wbm1 + 1280 * 320;

    // 0. all weights -> bf16 (zero-padded rows), single launch
    cvt_all<<<5280, 256, 0, stream>>>(qkv_w, pw, m1w, m2w, wb);
    // 1. CPE conv + residual -> x1b (bf16)
    cpe_tile<<<B_ * 40 * 16, 256, 0, stream>>>(x, cpe_w, cpe_b, x1b);
    // 2. LN1 -> bb1 (bf16)
    ln_kernel<__hip_bfloat16><<<B_ * Nn, 64, 0, stream>>>(x1b, ln1g, ln1b, bb1);
    // 3. QKV GEMM -> qkvb (BK=64, XCD-grouped)
    gemm_mfma<0, 0, 0, 1, 320><<<1024, 512, 0, stream>>>(bb1, wbq, qkv_b, nullptr,
                                                         nullptr, qkvb, QS, 960, 8);
    // 4. kv (+ softmax denominator) via MFMA
    kv_mfma<<<512, 256, 0, stream>>>(qkvb, kvp);
    kv_combine2<<<64, 256, 0, stream>>>(kvp, kv);
    // 5. domain gate
    dgate_kernel<<<B_, 320, 0, stream>>>(lbl, dw1, db1, dw2, db2, dg);
    // 6. fa = q @ kv (bf16 out)
    fa_kernel<<<B_ * 8 * 16, 256, 0, stream>>>(qkvb, kv, fab);
    // 7. crpe conv (k3/k5/k7 merged) + att combine -> bb1
    crpe_all<<<B_ * 40 * 16, 256, 0, stream>>>(qkvb, w3, b3, w5, b5, w7, b7,
                                               fab, dg, bb1);
    // 8. proj GEMM + residual(x1b) -> d_out, FUSED LN2 -> bb1 (pipelined, 10 steps)
    gemm_fulln<0, 2, 1, 0, 320, 1><<<512, 512, 0, stream>>>(bb1, wbp, pb, x1b,
                                                            out, nullptr, 320,
                                                            ln2g, ln2b, bb1);
    // 9. MLP1 + GELU -> gelub (BK=64, XCD-grouped)
    gemm_mfma<1, 0, 0, 1, 320><<<1280, 512, 0, stream>>>(bb1, wbm1, m1b, nullptr,
                                                         nullptr, gelub, 1280, 1280, 10);
    // 10. MLP2 + residual(d_out) -> d_out (pipelined fulln, 40 steps, gelu read once)
    gemm_fulln<0, 1, 1, 0, 1280, 0><<<512, 512, 0, stream>>>(gelub, wbm2, m2b, out,
                                                             out, nullptr, 320,
                                                             nullptr, nullptr, nullptr);
}

// Round 17
// 299.058 us; speedup vs baseline: 1.0316x; 1.0316x over previous
//
#include <hip/hip_runtime.h>
#include <hip/hip_bf16.h>
#include <math.h>
#include <type_traits>

#define B_    8
#define Nn    4096
#define Cc    320
#define QS    1024          // qkv row stride (padded from 960)
#define ATT_SCALE 0.15811388300841897f

typedef __attribute__((ext_vector_type(8))) short s8v;
typedef __attribute__((ext_vector_type(4))) float f4v;

__device__ __forceinline__ float bf2f(short u) {
    return __uint_as_float(((unsigned int)(unsigned short)u) << 16);
}
__device__ __forceinline__ short f2bf(float f) {
    return (short)__bfloat16_as_ushort(__float2bfloat16(f));
}
__device__ __forceinline__ float gelu_fast(float v) {
    float u = v * (0.7978845608f + 0.0356774081f * v * v);
    float e = __expf(2.f * u);
    float t = 1.f - 2.f / (e + 1.f);
    return 0.5f * v * (1.f + t);
}

typedef const __attribute__((address_space(1))) unsigned int* gp1_t;
typedef __attribute__((address_space(3))) unsigned int* lp3_t;
__device__ __forceinline__ void gload16(const void* g, void* l) {
    __builtin_amdgcn_global_load_lds((gp1_t)g, (lp3_t)l, 16, 0, 0);
}

// ---------------- all weights -> bf16 (padded), one launch ----------------
__global__ void cvt_all(const float* __restrict__ s0, const float* __restrict__ s1,
                        const float* __restrict__ s2, const float* __restrict__ s3,
                        __hip_bfloat16* __restrict__ d) {
    int i = blockIdx.x * 256 + threadIdx.x;
    if (i >= 1351680) return;
    const float* s; int j, rows, K;
    if (i < 327680)      { s = s0; j = i;          rows = 960;  K = 320; }
    else if (i < 450560) { s = s1; j = i - 327680; rows = 320;  K = 320; }
    else if (i < 860160) { s = s2; j = i - 450560; rows = 1280; K = 320; }
    else                 { s = s3; j = i - 860160; rows = 320;  K = 1280; }
    float v = (j / K < rows) ? s[j] : 0.f;
    d[i] = __float2bfloat16(v);
}

// ---------------- LayerNorm over C=320, one wave per token, bf16 out ----------------
template<typename T>
__global__ void ln_kernel(const T* __restrict__ x, const float* __restrict__ g,
                          const float* __restrict__ bt, __hip_bfloat16* __restrict__ out) {
    int bn = blockIdx.x;
    int lane = threadIdx.x;
    const T* row = x + (size_t)bn * Cc;
    float v[5];
    float s = 0.f, s2 = 0.f;
    #pragma unroll
    for (int i = 0; i < 5; ++i) {
        if constexpr (std::is_same<T, float>::value) v[i] = row[lane + 64 * i];
        else v[i] = bf2f(((const short*)row)[lane + 64 * i]);
        s += v[i];
        s2 += v[i] * v[i];
    }
    #pragma unroll
    for (int off = 32; off > 0; off >>= 1) {
        s  += __shfl_down(s, off);
        s2 += __shfl_down(s2, off);
    }
    s  = __shfl(s, 0);
    s2 = __shfl(s2, 0);
    float mean = s * (1.f / 320.f);
    float var  = s2 * (1.f / 320.f) - mean * mean;
    float rstd = rsqrtf(var + 1e-6f);
    __hip_bfloat16* orow = out + (size_t)bn * Cc;
    #pragma unroll
    for (int i = 0; i < 5; ++i) {
        int c = lane + 64 * i;
        orow[c] = __float2bfloat16((v[i] - mean) * rstd * g[c] + bt[c]);
    }
}

// ---------------- bf16 MFMA GEMM, 256x128 tile, BK=64 (R12 proven, 0 conflicts) ----
// 1-D grid with XCD-grouping: blocks sharing an A-panel get ids spaced 8 apart.
template<int ACT, int RES, int WF32, int WBF16, int KT>
__global__ __launch_bounds__(512) void gemm_mfma(
        const __hip_bfloat16* __restrict__ A, const __hip_bfloat16* __restrict__ W,
        const float* __restrict__ bias, const void* __restrict__ resv,
        float* __restrict__ outf, __hip_bfloat16* __restrict__ outb,
        int NS, int Nreal, int gy) {
    __shared__ __align__(16) short As[256 * 64];
    __shared__ __align__(16) short Bs[128 * 64];
    int bid = blockIdx.x;
    int grp8 = gy << 3;
    int grp = bid / grp8, rem = bid % grp8;
    int m0 = ((grp << 3) + (rem & 7)) << 8;
    int n0 = (rem >> 3) << 7;
    int tid = threadIdx.x;
    int w = tid >> 6, lane = tid & 63;
    int wr = w >> 1, wc = w & 1;
    int lrow = lane & 15, lk = lane >> 4;
    f4v acc[4][4];
    #pragma unroll
    for (int i = 0; i < 4; ++i)
        #pragma unroll
        for (int j = 0; j < 4; ++j) acc[i][j] = (f4v){0.f, 0.f, 0.f, 0.f};

    int srow = (w << 3) + (lane >> 3);
    int slot = lane & 7;

    #pragma unroll
    for (int k0 = 0; k0 < KT; k0 += 64) {
        __syncthreads();
        #pragma unroll
        for (int i = 0; i < 4; ++i) {
            int row = i * 64 + srow;
            int sk = (slot ^ (row & 7)) << 3;
            gload16(&A[(size_t)(m0 + row) * KT + k0 + sk], &As[i * 4096 + w * 512]);
        }
        #pragma unroll
        for (int i = 0; i < 2; ++i) {
            int row = i * 64 + srow;
            int sk = (slot ^ (row & 7)) << 3;
            gload16(&W[(size_t)(n0 + row) * KT + k0 + sk], &Bs[i * 4096 + w * 512]);
        }
        __syncthreads();
        #pragma unroll
        for (int ks = 0; ks < 2; ++ks) {
            s8v af[4], bf[4];
            #pragma unroll
            for (int mi = 0; mi < 4; ++mi) {
                int row = wr * 64 + mi * 16 + lrow;
                int s = (ks * 4 + lk) ^ (row & 7);
                af[mi] = *reinterpret_cast<const s8v*>(&As[row * 64 + s * 8]);
            }
            #pragma unroll
            for (int ni = 0; ni < 4; ++ni) {
                int row = wc * 64 + ni * 16 + lrow;
                int s = (ks * 4 + lk) ^ (row & 7);
                bf[ni] = *reinterpret_cast<const s8v*>(&Bs[row * 64 + s * 8]);
            }
            #pragma unroll
            for (int mi = 0; mi < 4; ++mi)
                #pragma unroll
                for (int ni = 0; ni < 4; ++ni)
                    acc[mi][ni] = __builtin_amdgcn_mfma_f32_16x16x32_bf16(bf[ni], af[mi], acc[mi][ni], 0, 0, 0);
        }
    }
    #pragma unroll
    for (int mi = 0; mi < 4; ++mi) {
        int m = m0 + wr * 64 + mi * 16 + lrow;
        #pragma unroll
        for (int ni = 0; ni < 4; ++ni) {
            int n = n0 + wc * 64 + ni * 16 + (lk << 2);
            if (n >= Nreal) continue;
            f4v v4 = acc[mi][ni];
            float4 bv = *reinterpret_cast<const float4*>(&bias[n]);
            v4[0] += bv.x; v4[1] += bv.y; v4[2] += bv.z; v4[3] += bv.w;
            if (RES == 1) {
                const float* res = (const float*)resv;
                float4 rv = *reinterpret_cast<const float4*>(&res[(size_t)m * NS + n]);
                v4[0] += rv.x; v4[1] += rv.y; v4[2] += rv.z; v4[3] += rv.w;
            } else if (RES == 2) {
                const short* res = (const short*)resv;
                short4 rv = *reinterpret_cast<const short4*>(&res[(size_t)m * NS + n]);
                v4[0] += bf2f(rv.x); v4[1] += bf2f(rv.y);
                v4[2] += bf2f(rv.z); v4[3] += bf2f(rv.w);
            }
            if (ACT == 1) {
                #pragma unroll
                for (int r = 0; r < 4; ++r) v4[r] = gelu_fast(v4[r]);
            }
            if (WF32)
                *reinterpret_cast<float4*>(&outf[(size_t)m * NS + n]) =
                    make_float4(v4[0], v4[1], v4[2], v4[3]);
            if (WBF16) {
                ushort4 u;
                u.x = (unsigned short)f2bf(v4[0]);
                u.y = (unsigned short)f2bf(v4[1]);
                u.z = (unsigned short)f2bf(v4[2]);
                u.w = (unsigned short)f2bf(v4[3]);
                *reinterpret_cast<ushort4*>(&outb[(size_t)m * NS + n]) = u;
            }
        }
    }
}

// ---------------- full-N GEMM (N=320): A read ONCE; optional fused LayerNorm ----------
// tile M=64 x N=320, 512 threads, 8 waves 2m x 4n. (R12 proven, BK=64, 0 conflicts.)
template<int ACT, int RES, int WF32, int WBF16, int KT, int LN>
__global__ __launch_bounds__(512) void gemm_fulln(
        const __hip_bfloat16* __restrict__ A, const __hip_bfloat16* __restrict__ W,
        const float* __restrict__ bias, const void* __restrict__ resv,
        float* __restrict__ outf, __hip_bfloat16* __restrict__ outb, int NS,
        const float* __restrict__ lng, const float* __restrict__ lnb,
        __hip_bfloat16* __restrict__ lnout) {
    __shared__ __align__(16) short As[64 * 64];
    __shared__ __align__(16) short Ws[320 * 64];
    int tid = threadIdx.x;
    int m0 = blockIdx.x << 6;
    int w = tid >> 6, lane = tid & 63;
    int wr = w >> 2, wc = w & 3;
    int lrow = lane & 15, lk = lane >> 4;
    f4v acc[2][5];
    #pragma unroll
    for (int i = 0; i < 2; ++i)
        #pragma unroll
        for (int j = 0; j < 5; ++j) acc[i][j] = (f4v){0.f, 0.f, 0.f, 0.f};

    int srow = tid >> 3;
    int slot = tid & 7;

    #pragma unroll
    for (int k0 = 0; k0 < KT; k0 += 64) {
        __syncthreads();
        {
            int sk = (slot ^ (srow & 7)) << 3;
            gload16(&A[(size_t)(m0 + srow) * KT + k0 + sk], &As[w * 512]);
        }
        #pragma unroll
        for (int i = 0; i < 5; ++i) {
            int row = i * 64 + srow;
            int sk = (slot ^ (row & 7)) << 3;
            gload16(&W[(size_t)row * KT + k0 + sk], &Ws[i * 4096 + w * 512]);
        }
        __syncthreads();
        #pragma unroll
        for (int ks = 0; ks < 2; ++ks) {
            s8v af[2], bf[5];
            #pragma unroll
            for (int mi = 0; mi < 2; ++mi) {
                int row = wr * 32 + mi * 16 + lrow;
                int s = (ks * 4 + lk) ^ (row & 7);
                af[mi] = *reinterpret_cast<const s8v*>(&As[row * 64 + s * 8]);
            }
            #pragma unroll
            for (int ni = 0; ni < 5; ++ni) {
                int row = wc * 80 + ni * 16 + lrow;
                int s = (ks * 4 + lk) ^ (row & 7);
                bf[ni] = *reinterpret_cast<const s8v*>(&Ws[row * 64 + s * 8]);
            }
            #pragma unroll
            for (int mi = 0; mi < 2; ++mi)
                #pragma unroll
                for (int ni = 0; ni < 5; ++ni)
                    acc[mi][ni] = __builtin_amdgcn_mfma_f32_16x16x32_bf16(bf[ni], af[mi], acc[mi][ni], 0, 0, 0);
        }
    }
    float psum[2] = {0.f, 0.f}, psq[2] = {0.f, 0.f};
    #pragma unroll
    for (int mi = 0; mi < 2; ++mi) {
        int rl = wr * 32 + mi * 16 + lrow;
        int m = m0 + rl;
        #pragma unroll
        for (int ni = 0; ni < 5; ++ni) {
            int n = wc * 80 + ni * 16 + (lk << 2);
            f4v v4 = acc[mi][ni];
            float4 bv = *reinterpret_cast<const float4*>(&bias[n]);
            v4[0] += bv.x; v4[1] += bv.y; v4[2] += bv.z; v4[3] += bv.w;
            if (RES == 1) {
                const float* res = (const float*)resv;
                float4 rv = *reinterpret_cast<const float4*>(&res[(size_t)m * NS + n]);
                v4[0] += rv.x; v4[1] += rv.y; v4[2] += rv.z; v4[3] += rv.w;
            } else if (RES == 2) {
                const short* res = (const short*)resv;
                short4 rv = *reinterpret_cast<const short4*>(&res[(size_t)m * NS + n]);
                v4[0] += bf2f(rv.x); v4[1] += bf2f(rv.y);
                v4[2] += bf2f(rv.z); v4[3] += bf2f(rv.w);
            }
            if (ACT == 1) {
                #pragma unroll
                for (int r = 0; r < 4; ++r) v4[r] = gelu_fast(v4[r]);
            }
            if (WF32)
                *reinterpret_cast<float4*>(&outf[(size_t)m * NS + n]) =
                    make_float4(v4[0], v4[1], v4[2], v4[3]);
            if (WBF16) {
                ushort4 u;
                u.x = (unsigned short)f2bf(v4[0]);
                u.y = (unsigned short)f2bf(v4[1]);
                u.z = (unsigned short)f2bf(v4[2]);
                u.w = (unsigned short)f2bf(v4[3]);
                *reinterpret_cast<ushort4*>(&outb[(size_t)m * NS + n]) = u;
            }
            if (LN) {
                acc[mi][ni] = v4;
                psum[mi] += v4[0] + v4[1] + v4[2] + v4[3];
                psq[mi]  += v4[0]*v4[0] + v4[1]*v4[1] + v4[2]*v4[2] + v4[3]*v4[3];
            }
        }
    }
    if (LN) {
        __syncthreads();
        float* red = (float*)As;
        #pragma unroll
        for (int mi = 0; mi < 2; ++mi) {
            int rl = wr * 32 + mi * 16 + lrow;
            red[(rl * 16 + wc * 4 + lk) * 2]     = psum[mi];
            red[(rl * 16 + wc * 4 + lk) * 2 + 1] = psq[mi];
        }
        __syncthreads();
        float* st = (float*)Ws;
        if (tid < 64) {
            float s = 0.f, q = 0.f;
            #pragma unroll
            for (int p = 0; p < 16; ++p) {
                s += red[(tid * 16 + p) * 2];
                q += red[(tid * 16 + p) * 2 + 1];
            }
            float mean = s * (1.f / 320.f);
            float var  = q * (1.f / 320.f) - mean * mean;
            st[tid * 2]     = mean;
            st[tid * 2 + 1] = rsqrtf(var + 1e-6f);
        }
        __syncthreads();
        #pragma unroll
        for (int mi = 0; mi < 2; ++mi) {
            int rl = wr * 32 + mi * 16 + lrow;
            int m = m0 + rl;
            float mean = st[rl * 2], rstd = st[rl * 2 + 1];
            #pragma unroll
            for (int ni = 0; ni < 5; ++ni) {
                int n = wc * 80 + ni * 16 + (lk << 2);
                float4 g4 = *reinterpret_cast<const float4*>(&lng[n]);
                float4 b4 = *reinterpret_cast<const float4*>(&lnb[n]);
                f4v v4 = acc[mi][ni];
                ushort4 u;
                u.x = (unsigned short)f2bf((v4[0] - mean) * rstd * g4.x + b4.x);
                u.y = (unsigned short)f2bf((v4[1] - mean) * rstd * g4.y + b4.y);
                u.z = (unsigned short)f2bf((v4[2] - mean) * rstd * g4.z + b4.z);
                u.w = (unsigned short)f2bf((v4[3] - mean) * rstd * g4.w + b4.w);
                *reinterpret_cast<ushort4*>(&lnout[(size_t)m * Cc + n]) = u;
            }
        }
    }
}

// ---------------- CPE depthwise conv (k=3) + residual from LDS tile -> bf16 ----------
__global__ __launch_bounds__(256) void cpe_tile(
        const float* __restrict__ src, const float* __restrict__ wts,
        const float* __restrict__ bias, __hip_bfloat16* __restrict__ outb) {
    constexpr int P = 1, S = 18;
    __shared__ float vt[S * S * 8];
    __shared__ float ws_[8 * 9];
    int blk = blockIdx.x;
    int tile = blk & 15;
    int g  = (blk >> 4) % 40;
    int b  = (blk >> 4) / 40;
    int ty0 = (tile >> 2) << 4;
    int tx0 = (tile & 3) << 4;
    int c0 = g * 8;
    int tid = threadIdx.x;
    for (int e = tid; e < 72; e += 256) ws_[e] = wts[c0 * 9 + e];
    const float* sb = src + (size_t)b * Nn * Cc + c0;
    for (int e = tid; e < S * S; e += 256) {
        int hy = e / S, hx = e % S;
        int gy = ty0 - P + hy, gx = tx0 - P + hx;
        float px8[8];
        #pragma unroll
        for (int j = 0; j < 8; ++j) px8[j] = 0.f;
        if ((unsigned)gy < 64u && (unsigned)gx < 64u) {
            const float* p = &sb[(size_t)((gy << 6) + gx) * Cc];
            float4 lo = reinterpret_cast<const float4*>(p)[0];
            float4 hi = reinterpret_cast<const float4*>(p)[1];
            px8[0] = lo.x; px8[1] = lo.y; px8[2] = lo.z; px8[3] = lo.w;
            px8[4] = hi.x; px8[5] = hi.y; px8[6] = hi.z; px8[7] = hi.w;
        }
        #pragma unroll
        for (int j = 0; j < 8; ++j) vt[e * 8 + j] = px8[j];
    }
    __syncthreads();
    int cl  = tid & 7;
    int px  = (tid >> 3) & 15;
    int pyh = tid >> 7;
    int c = c0 + cl;
    float acc[8];
    float bval = bias[c];
    #pragma unroll
    for (int j = 0; j < 8; ++j) acc[j] = bval;
    #pragma unroll
    for (int dx = 0; dx < 3; ++dx) {
        float col[10];
        #pragma unroll
        for (int i = 0; i < 10; ++i)
            col[i] = vt[((pyh * 8 + i) * S + (px + dx)) * 8 + cl];
        #pragma unroll
        for (int j = 0; j < 8; ++j)
            #pragma unroll
            for (int dy = 0; dy < 3; ++dy)
                acc[j] += col[j + dy] * ws_[cl * 9 + dy * 3 + dx];
    }
    #pragma unroll
    for (int j = 0; j < 8; ++j) {
        int n = ((ty0 + pyh * 8 + j) << 6) + tx0 + px;
        size_t bn = (size_t)b * Nn + n;
        float ctr = vt[((pyh * 8 + j + P) * S + (px + P)) * 8 + cl];
        outb[bn * Cc + c] = __float2bfloat16(acc[j] + ctr);
    }
}

// ---------------- merged crpe conv (k3/k5/k7 in ONE launch) + att combine ------------
template<int KSZ>
__device__ __forceinline__ void crpe_body(
        float* vt, float* ws_, int tile, int b, int c0,
        const short* __restrict__ qkv, const float* __restrict__ wts,
        const float* __restrict__ bias,
        const short* __restrict__ fa0, const float* __restrict__ dg,
        short* __restrict__ outb) {
    constexpr int P = KSZ / 2;
    constexpr int S = 16 + 2 * P;
    int ty0 = (tile >> 2) << 4;
    int tx0 = (tile & 3) << 4;
    int tid = threadIdx.x;
    for (int e = tid; e < 8 * KSZ * KSZ; e += 256) ws_[e] = wts[e];
    const short* sb = qkv + (size_t)b * Nn * QS + 640 + c0;
    for (int e = tid; e < S * S; e += 256) {
        int hy = e / S, hx = e % S;
        int gy = ty0 - P + hy, gx = tx0 - P + hx;
        float px8[8];
        #pragma unroll
        for (int j = 0; j < 8; ++j) px8[j] = 0.f;
        if ((unsigned)gy < 64u && (unsigned)gx < 64u) {
            s8v v8 = *reinterpret_cast<const s8v*>(&sb[(size_t)((gy << 6) + gx) * QS]);
            #pragma unroll
            for (int j = 0; j < 8; ++j) px8[j] = bf2f(v8[j]);
        }
        #pragma unroll
        for (int j = 0; j < 8; ++j) vt[e * 8 + j] = px8[j];
    }
    __syncthreads();
    int cl  = tid & 7;
    int px  = (tid >> 3) & 15;
    int pyh = tid >> 7;
    int c = c0 + cl;
    float acc[8];
    float bval = bias[cl];
    #pragma unroll
    for (int j = 0; j < 8; ++j) acc[j] = bval;
    #pragma unroll
    for (int dx = 0; dx < KSZ; ++dx) {
        float col[8 + KSZ - 1];
        #pragma unroll
        for (int i = 0; i < 8 + KSZ - 1; ++i)
            col[i] = vt[((pyh * 8 + i) * S + (px + dx)) * 8 + cl];
        #pragma unroll
        for (int j = 0; j < 8; ++j)
            #pragma unroll
            for (int dy = 0; dy < KSZ; ++dy)
                acc[j] += col[j + dy] * ws_[cl * KSZ * KSZ + dy * KSZ + dx];
    }
    float dgv = dg[(size_t)b * Cc + c];
    #pragma unroll
    for (int j = 0; j < 8; ++j) {
        int n = ((ty0 + pyh * 8 + j) << 6) + tx0 + px;
        size_t bn = (size_t)b * Nn + n;
        float qv  = bf2f(qkv[bn * QS + c]);
        float fav = bf2f(fa0[bn * Cc + c]);
        float r = dgv * (ATT_SCALE * fav + qv * acc[j]);
        outb[bn * Cc + c] = __float2bfloat16(r);
    }
}

__global__ __launch_bounds__(256) void crpe_all(
        const __hip_bfloat16* __restrict__ qkv,
        const float* __restrict__ w3, const float* __restrict__ b3,
        const float* __restrict__ w5, const float* __restrict__ b5,
        const float* __restrict__ w7, const float* __restrict__ b7,
        const __hip_bfloat16* __restrict__ fa, const float* __restrict__ dg,
        __hip_bfloat16* __restrict__ outb) {
    __shared__ float vt[22 * 22 * 8];
    __shared__ float ws_[8 * 49];
    int blk = blockIdx.x;
    int tile = blk & 15;
    int g = (blk >> 4) % 40;
    int b = (blk >> 4) / 40;
    int c0 = g * 8;
    if (g < 10)
        crpe_body<3>(vt, ws_, tile, b, c0, (const short*)qkv,
                     w3 + c0 * 9, b3 + c0, (const short*)fa, dg, (short*)outb);
    else if (g < 25)
        crpe_body<5>(vt, ws_, tile, b, c0, (const short*)qkv,
                     w5 + (c0 - 80) * 25, b5 + (c0 - 80), (const short*)fa, dg, (short*)outb);
    else
        crpe_body<7>(vt, ws_, tile, b, c0, (const short*)qkv,
                     w7 + (c0 - 200) * 49, b7 + (c0 - 200), (const short*)fa, dg, (short*)outb);
}

// ---------------- kv + softmax-denominator via MFMA ----------------
__global__ __launch_bounds__(256) void kv_mfma(const __hip_bfloat16* __restrict__ qkv,
                                               float* __restrict__ kvp) {
    __shared__ short lds[4 * 2 * 48 * 66];
    int blk = blockIdx.x;
    int s = blk & 7;
    int bh = blk >> 3;
    int h = bh & 7, b = bh >> 3;
    int tid = threadIdx.x;
    int w = tid >> 6, lane = tid & 63;
    short* ke_t = lds + w * 2 * 48 * 66;
    short* vv_t = ke_t + 48 * 66;
    for (int e = lane; e < 8 * 66; e += 64) {
        ke_t[40 * 66 + e] = 0;
        vv_t[40 * 66 + e] = 0;
    }
    for (int n = lane; n < 66; n += 64) vv_t[40 * 66 + n] = (short)0x3F80;

    const short* kb = (const short*)qkv + (size_t)b * Nn * QS + 320 + h * 40;
    const short* vb = kb + 320;
    int col0 = lane & 15, kq = lane >> 4;
    f4v acc[3][3];
    #pragma unroll
    for (int i = 0; i < 3; ++i)
        #pragma unroll
        for (int j = 0; j < 3; ++j) acc[i][j] = (f4v){0.f, 0.f, 0.f, 0.f};

    for (int t = w; t < 8; t += 4) {
        int n0 = s * 512 + t * 64;
        for (int e = lane; e < 320; e += 64) {
            int nl = e / 5, oct = e % 5;
            size_t go = (size_t)(n0 + nl) * QS + oct * 8;
            s8v k8 = *reinterpret_cast<const s8v*>(kb + go);
            s8v v8 = *reinterpret_cast<const s8v*>(vb + go);
            #pragma unroll
            for (int j = 0; j < 8; ++j) {
                ke_t[(oct * 8 + j) * 66 + nl] = f2bf(__expf(bf2f(k8[j])));
                vv_t[(oct * 8 + j) * 66 + nl] = v8[j];
            }
        }
        __syncthreads();
        #pragma unroll
        for (int ks = 0; ks < 2; ++ks) {
            s8v af[3], bfr[3];
            #pragma unroll
            for (int mt = 0; mt < 3; ++mt)
                af[mt] = *reinterpret_cast<const s8v*>(ke_t + (mt * 16 + col0) * 66 + ks * 32 + kq * 8);
            #pragma unroll
            for (int nt = 0; nt < 3; ++nt)
                bfr[nt] = *reinterpret_cast<const s8v*>(vv_t + (nt * 16 + col0) * 66 + ks * 32 + kq * 8);
            #pragma unroll
            for (int mt = 0; mt < 3; ++mt)
                #pragma unroll
                for (int nt = 0; nt < 3; ++nt)
                    acc[mt][nt] = __builtin_amdgcn_mfma_f32_16x16x32_bf16(af[mt], bfr[nt], acc[mt][nt], 0, 0, 0);
        }
        __syncthreads();
    }
    float* red = (float*)lds;
    #pragma unroll
    for (int mt = 0; mt < 3; ++mt) {
        #pragma unroll
        for (int nt = 0; nt < 3; ++nt) {
            #pragma unroll
            for (int r = 0; r < 4; ++r) {
                int ch = mt * 16 + kq * 4 + r;
                int cv = nt * 16 + col0;
                if (ch < 40) red[w * 1920 + ch * 48 + cv] = acc[mt][nt][r];
            }
        }
    }
    __syncthreads();
    for (int p = tid; p < 1920; p += 256) {
        float sv = red[p] + red[1920 + p] + red[2 * 1920 + p] + red[3 * 1920 + p];
        kvp[(size_t)blk * 1920 + p] = sv;
    }
}

__global__ void kv_combine2(const float* __restrict__ kvp, float* __restrict__ kv) {
    int bh = blockIdx.x;
    int tid = threadIdx.x;
    __shared__ float sinv[40];
    if (tid < 40) {
        float S = 0.f;
        for (int s2 = 0; s2 < 8; ++s2)
            S += kvp[(size_t)(bh * 8 + s2) * 1920 + tid * 48 + 40];
        sinv[tid] = 1.f / S;
    }
    __syncthreads();
    for (int p = tid; p < 1600; p += 256) {
        int ch = p / 40, cv = p % 40;
        float v = 0.f;
        for (int s2 = 0; s2 < 8; ++s2)
            v += kvp[(size_t)(bh * 8 + s2) * 1920 + ch * 48 + cv];
        kv[(size_t)bh * 1600 + p] = v * sinv[ch];
    }
}

// ---------------- domain gate ----------------
__global__ void dgate_kernel(const float* __restrict__ lbl, const float* __restrict__ w1,
                             const float* __restrict__ b1, const float* __restrict__ w2,
                             const float* __restrict__ b2, float* __restrict__ dg) {
    int b = blockIdx.x;
    int tid = threadIdx.x;
    __shared__ float hid[160];
    __shared__ float dd[320];
    if (tid < 160) {
        float a = b1[tid];
        for (int d = 0; d < 4; ++d) a += w1[tid * 4 + d] * lbl[b * 4 + d];
        hid[tid] = fmaxf(a, 0.f);
    }
    __syncthreads();
    float a = b2[tid];
    for (int j = 0; j < 160; ++j) a += w2[tid * 160 + j] * hid[j];
    dd[tid] = a;
    __syncthreads();
    if (tid < 40) {
        float M = -1e30f;
        for (int h2 = 0; h2 < 8; ++h2) M = fmaxf(M, dd[h2 * 40 + tid]);
        float S = 0.f;
        float e[8];
        for (int h2 = 0; h2 < 8; ++h2) { e[h2] = __expf(dd[h2 * 40 + tid] - M); S += e[h2]; }
        float inv = 1.f / S;
        for (int h2 = 0; h2 < 8; ++h2) dg[b * 320 + h2 * 40 + tid] = e[h2] * inv;
    }
}

// ---------------- fa = q @ kv, one token per thread, bf16 out ----------------
__global__ __launch_bounds__(256) void fa_kernel(const __hip_bfloat16* __restrict__ qkv,
        const float* __restrict__ kvmat, __hip_bfloat16* __restrict__ fa) {
    __shared__ float kvs[1600];
    int blk = blockIdx.x;
    int chunk = blk & 15;
    int bh = blk >> 4;
    int h = bh & 7, b = bh >> 3;
    int tid = threadIdx.x;
    for (int e = tid; e < 1600; e += 256) kvs[e] = kvmat[(size_t)bh * 1600 + e];
    __syncthreads();
    int n = chunk * 256 + tid;
    const short* qr = (const short*)qkv + (size_t)(b * Nn + n) * QS + h * 40;
    float q[40];
    #pragma unroll
    for (int i = 0; i < 5; ++i) {
        s8v v8 = reinterpret_cast<const s8v*>(qr)[i];
        #pragma unroll
        for (int j = 0; j < 8; ++j) q[i * 8 + j] = bf2f(v8[j]);
    }
    float o[40];
    #pragma unroll
    for (int cv = 0; cv < 40; ++cv) o[cv] = 0.f;
    #pragma unroll
    for (int ch = 0; ch < 40; ++ch) {
        float qv = q[ch];
        #pragma unroll
        for (int cv = 0; cv < 40; ++cv)
            o[cv] += qv * kvs[ch * 40 + cv];
    }
    short* fr = (short*)fa + (size_t)(b * Nn + n) * 320 + h * 40;
    #pragma unroll
    for (int i = 0; i < 5; ++i) {
        s8v u;
        #pragma unroll
        for (int j = 0; j < 8; ++j) u[j] = f2bf(o[i * 8 + j]);
        *reinterpret_cast<s8v*>(fr + i * 8) = u;
    }
}

extern "C" void kernel_launch(void* const* d_in, const int* in_sizes, int n_in,
                              void* d_out, int out_size, void* d_ws, size_t ws_size,
                              hipStream_t stream) {
    const float* x     = (const float*)d_in[0];
    const float* lbl   = (const float*)d_in[1];
    const float* cpe_w = (const float*)d_in[2];
    const float* cpe_b = (const float*)d_in[3];
    const float* ln1g  = (const float*)d_in[4];
    const float* ln1b  = (const float*)d_in[5];
    const float* qkv_w = (const float*)d_in[6];
    const float* qkv_b = (const float*)d_in[7];
    const float* w3    = (const float*)d_in[8];
    const float* b3    = (const float*)d_in[9];
    const float* w5    = (const float*)d_in[10];
    const float* b5    = (const float*)d_in[11];
    const float* w7    = (const float*)d_in[12];
    const float* b7    = (const float*)d_in[13];
    const float* dw1   = (const float*)d_in[14];
    const float* db1   = (const float*)d_in[15];
    const float* dw2   = (const float*)d_in[16];
    const float* db2   = (const float*)d_in[17];
    const float* pw    = (const float*)d_in[18];
    const float* pb    = (const float*)d_in[19];
    const float* ln2g  = (const float*)d_in[20];
    const float* ln2b  = (const float*)d_in[21];
    const float* m1w   = (const float*)d_in[22];
    const float* m1b   = (const float*)d_in[23];
    const float* m2w   = (const float*)d_in[24];
    const float* m2b   = (const float*)d_in[25];
    float* out = (float*)d_out;

    float* ws = (float*)d_ws;
    __hip_bfloat16* x1b  = (__hip_bfloat16*)ws; ws += 5242880;
    __hip_bfloat16* qkvb = (__hip_bfloat16*)ws; ws += 16777216;
    float* big  = ws; ws += 20971520;
    __hip_bfloat16* gelub = (__hip_bfloat16*)big;
    __hip_bfloat16* fab   = (__hip_bfloat16*)ws; ws += 5242880;
    __hip_bfloat16* bb1   = (__hip_bfloat16*)ws; ws += 5242880;
    __hip_bfloat16* wb    = (__hip_bfloat16*)ws; ws += 675840;
    float* kvp  = ws; ws += 983040;
    float* kv   = ws; ws += 102400;
    float* dg   = ws; ws += 2560;
    __hip_bfloat16* wbq  = wb;
    __hip_bfloat16* wbp  = wbq  + 1024 * 320;
    __hip_bfloat16* wbm1 = wbp  + 384 * 320;
    __hip_bfloat16* wbm2 = wbm1 + 1280 * 320;

    // 0. all weights -> bf16 (zero-padded rows), single launch
    cvt_all<<<5280, 256, 0, stream>>>(qkv_w, pw, m1w, m2w, wb);
    // 1. CPE conv + residual -> x1b (bf16)
    cpe_tile<<<B_ * 40 * 16, 256, 0, stream>>>(x, cpe_w, cpe_b, x1b);
    // 2. LN1 -> bb1 (bf16)
    ln_kernel<__hip_bfloat16><<<B_ * Nn, 64, 0, stream>>>(x1b, ln1g, ln1b, bb1);
    // 3. QKV GEMM -> qkvb (BK=64, XCD-grouped)
    gemm_mfma<0, 0, 0, 1, 320><<<1024, 512, 0, stream>>>(bb1, wbq, qkv_b, nullptr,
                                                         nullptr, qkvb, QS, 960, 8);
    // 4. kv (+ softmax denominator) via MFMA
    kv_mfma<<<512, 256, 0, stream>>>(qkvb, kvp);
    kv_combine2<<<64, 256, 0, stream>>>(kvp, kv);
    // 5. domain gate
    dgate_kernel<<<B_, 320, 0, stream>>>(lbl, dw1, db1, dw2, db2, dg);
    // 6. fa = q @ kv (bf16 out)
    fa_kernel<<<B_ * 8 * 16, 256, 0, stream>>>(qkvb, kv, fab);
    // 7. crpe conv (k3/k5/k7 merged) + att combine -> bb1
    crpe_all<<<B_ * 40 * 16, 256, 0, stream>>>(qkvb, w3, b3, w5, b5, w7, b7,
                                               fab, dg, bb1);
    // 8. proj GEMM + residual(x1b) -> d_out, FUSED LN2 -> bb1
    gemm_fulln<0, 2, 1, 0, 320, 1><<<512, 512, 0, stream>>>(bb1, wbp, pb, x1b,
                                                            out, nullptr, 320,
                                                            ln2g, ln2b, bb1);
    // 9. MLP1 + GELU -> gelub (BK=64, XCD-grouped)
    gemm_mfma<1, 0, 0, 1, 320><<<1280, 512, 0, stream>>>(bb1, wbm1, m1b, nullptr,
                                                         nullptr, gelub, 1280, 1280, 10);
    // 10. MLP2 + residual(d_out) -> d_out (fulln: gelu read ONCE)
    gemm_fulln<0, 1, 1, 0, 1280, 0><<<512, 512, 0, stream>>>(gelub, wbm2, m2b, out,
                                                             out, nullptr, 320,
                                                             nullptr, nullptr, nullptr);
}